// Round 1
// baseline (6937.801 us; speedup 1.0000x reference)
//
#include <hip/hip_runtime.h>
#include <math.h>

// Problem constants (B,T,E)=(4,2048,2048), NH=16, NKV=4, HD=128
constexpr int Bc   = 4;
constexpr int Tc   = 2048;
constexpr int Ec   = 2048;
constexpr int NHc  = 16;
constexpr int NKVc = 4;
constexpr int HDc  = 128;
constexpr int KVEc = NKVc * HDc; // 512

// ---------------------------------------------------------------------------
// fp32 GEMM: C[M,N] = A[M,K] @ W[K,N] + bias[N]
// 64x64 block, BK=16, 256 threads, 4x4 micro-tile.
// ---------------------------------------------------------------------------
__global__ __launch_bounds__(256)
void gemm_bias_f32(const float* __restrict__ A, const float* __restrict__ W,
                   const float* __restrict__ bias, float* __restrict__ C,
                   int M, int N, int K)
{
    __shared__ float As[16][64];   // As[k][m] (transposed store)
    __shared__ float Ws[16][64];   // Ws[k][n]
    const int t  = threadIdx.x;
    const int bm = blockIdx.x * 64;
    const int bn = blockIdx.y * 64;
    const int tx = t & 15;         // 16 col groups of 4
    const int ty = t >> 4;         // 16 row groups of 4
    const int rowA = t >> 2;       // 0..63
    const int kcA  = (t & 3) << 2; // 0,4,8,12
    const int rowW = t >> 4;       // 0..15
    const int colW = (t & 15) << 2;

    float acc[4][4] = {};

    for (int k0 = 0; k0 < K; k0 += 16) {
        float4 a4 = *(const float4*)(A + (size_t)(bm + rowA) * K + (k0 + kcA));
        float4 w4 = *(const float4*)(W + (size_t)(k0 + rowW) * N + (bn + colW));
        __syncthreads();                       // protect previous tile's reads
        As[kcA + 0][rowA] = a4.x;
        As[kcA + 1][rowA] = a4.y;
        As[kcA + 2][rowA] = a4.z;
        As[kcA + 3][rowA] = a4.w;
        *(float4*)&Ws[rowW][colW] = w4;
        __syncthreads();
        #pragma unroll
        for (int k = 0; k < 16; ++k) {
            float4 av = *(const float4*)&As[k][ty << 2]; // broadcast across tx
            float4 wv = *(const float4*)&Ws[k][tx << 2]; // 2-way bank (free)
            float a0[4] = {av.x, av.y, av.z, av.w};
            float w0[4] = {wv.x, wv.y, wv.z, wv.w};
            #pragma unroll
            for (int i = 0; i < 4; ++i)
                #pragma unroll
                for (int j = 0; j < 4; ++j)
                    acc[i][j] = fmaf(a0[i], w0[j], acc[i][j]);
        }
    }
    const int colb = bn + (tx << 2);
    float4 bv = *(const float4*)(bias + colb);
    #pragma unroll
    for (int i = 0; i < 4; ++i) {
        float4 o = { acc[i][0] + bv.x, acc[i][1] + bv.y,
                     acc[i][2] + bv.z, acc[i][3] + bv.w };
        *(float4*)(C + (size_t)(bm + (ty << 2) + i) * N + colb) = o;
    }
}

// ---------------------------------------------------------------------------
// RoPE + remap: X2d (B,T,512) -> Y (B,NKV,T,HD)
//   k[b,kh,tk,d] = X2d[b, kh*512 + tk/4, 128*(tk%4) + d], rotated by tk*theta_j
// One thread per (b,kh,tk,pair j). theta_j = 10000^(-j/64) (exact f32 exponent)
// ---------------------------------------------------------------------------
__global__ __launch_bounds__(256)
void rope_remap(const float* __restrict__ X2d, float* __restrict__ Y)
{
    const int idx = blockIdx.x * 256 + threadIdx.x; // B*NKV*T*64 = 2,097,152
    const int j  = idx & 63;
    const int tk = (idx >> 6) & (Tc - 1);
    const int kh = (idx >> 17) & (NKVc - 1);
    const int bb = idx >> 19;
    const int row = (kh << 9) + (tk >> 2);        // kh*512 + tk/4
    const int col = ((tk & 3) << 7) + (j << 1);   // 128*(tk%4) + 2j
    const float* src = X2d + ((size_t)bb * Tc + row) * KVEc + col;
    const float a = src[0];
    const float b = src[1];
    const float theta = powf(10000.0f, -(float)j * (1.0f / 64.0f));
    const float ang = (float)tk * theta;          // f32 product, matches np
    float s, c;
    sincosf(ang, &s, &c);
    float* dst = Y + (((size_t)bb * NKVc + kh) * Tc + tk) * HDc + (j << 1);
    dst[0] = a * c - b * s;
    dst[1] = a * s + b * c;
}

// ---------------------------------------------------------------------------
// Attention (fp32, online softmax). WG = 256 threads = 16 queries x 128 dims.
// Q block for (b,h,qb) is ONE contiguous row of Q2d: row h*128+qb, cols 0..2047.
// KV head = h % 4 (jnp.tile semantics). Masked scores = 1e-9 exactly.
// scores = (q.k) * sqrt(128)  [multiply!]
// LDS strides padded (132 / 66) to avoid 128-stride bank conflicts.
// ---------------------------------------------------------------------------
__global__ __launch_bounds__(256)
void attn_f32(const float* __restrict__ Q2d, const float* __restrict__ Kro,
              const float* __restrict__ Vro, const int* __restrict__ mask,
              float* __restrict__ AO)
{
    const int qb = blockIdx.x;  // 0..127  (query block of 16)
    const int h  = blockIdx.y;  // 0..15
    const int bb = blockIdx.z;  // 0..3
    const int t  = threadIdx.x;
    const int kh = h & (NKVc - 1);

    __shared__ float Qs[16 * 132];
    __shared__ float Ks[64 * 132];
    __shared__ float Vs[64 * 132];
    __shared__ float S[16 * 66];
    __shared__ float mrow[16], lrow[16], arow[16];

    // Load Q block: one contiguous 2048-float row of Q2d
    {
        const float4* qsrc = (const float4*)(Q2d + ((size_t)bb * Tc + (h << 7) + qb) * Ec);
        #pragma unroll
        for (int i = 0; i < 2; ++i) {
            int e = i * 256 + t;             // 0..511 float4s
            float4 v = qsrc[e];
            int r  = e >> 5;                 // 32 float4 per 128-dim row
            int c4 = e & 31;
            *(float4*)&Qs[r * 132 + (c4 << 2)] = v;
        }
    }
    if (t < 16) { mrow[t] = -INFINITY; lrow[t] = 0.0f; }

    const int qi = t >> 4;            // 0..15 query within block
    const int c  = t & 15;            // 0..15 lane group
    const int tq = (qb << 4) + qi;
    const int* mrp = mask + ((size_t)bb * Tc + tq) * Tc;
    const float* kbase = Kro + ((size_t)bb * NKVc + kh) * (size_t)Tc * HDc;
    const float* vbase = Vro + ((size_t)bb * NKVc + kh) * (size_t)Tc * HDc;
    const float scale = 11.313708498984761f;  // sqrt(128)

    float4 accA = {0,0,0,0}, accB = {0,0,0,0}; // dims c*4..+3 and 64+c*4..+3

    for (int kt = 0; kt < Tc / 64; ++kt) {
        __syncthreads();   // protect previous tile's Ks/Vs/S reads
        const float4* kg = (const float4*)(kbase + (size_t)kt * 64 * HDc);
        const float4* vg = (const float4*)(vbase + (size_t)kt * 64 * HDc);
        #pragma unroll
        for (int i = 0; i < 8; ++i) {
            int e = i * 256 + t;          // 0..2047 float4s
            int r  = e >> 5;
            int c4 = e & 31;
            float4 kv = kg[e];
            float4 vv = vg[e];
            *(float4*)&Ks[r * 132 + (c4 << 2)] = kv;
            *(float4*)&Vs[r * 132 + (c4 << 2)] = vv;
        }
        __syncthreads();

        // Scores: thread (qi,c) computes keys c, c+16, c+32, c+48
        float dot[4] = {0,0,0,0};
        #pragma unroll 8
        for (int d4 = 0; d4 < 32; ++d4) {
            float4 q4 = *(const float4*)&Qs[qi * 132 + (d4 << 2)];
            #pragma unroll
            for (int s2 = 0; s2 < 4; ++s2) {
                float4 k4 = *(const float4*)&Ks[(c + (s2 << 4)) * 132 + (d4 << 2)];
                dot[s2] = fmaf(q4.x, k4.x, dot[s2]);
                dot[s2] = fmaf(q4.y, k4.y, dot[s2]);
                dot[s2] = fmaf(q4.z, k4.z, dot[s2]);
                dot[s2] = fmaf(q4.w, k4.w, dot[s2]);
            }
        }
        #pragma unroll
        for (int s2 = 0; s2 < 4; ++s2) {
            int kj = c + (s2 << 4);
            int mv = mrp[(kt << 6) + kj];
            S[qi * 66 + kj] = (mv == 0) ? 1e-9f : dot[s2] * scale;
        }
        __syncthreads();

        // Online softmax update (one thread per query row; 64 entries)
        if (t < 16) {
            float mo = mrow[t];
            float rm = mo;
            for (int j2 = 0; j2 < 64; ++j2) rm = fmaxf(rm, S[t * 66 + j2]);
            float al = __expf(mo - rm);   // exp(-inf)=0 on first tile
            float sum = 0.0f;
            for (int j2 = 0; j2 < 64; ++j2) {
                float p = __expf(S[t * 66 + j2] - rm);
                S[t * 66 + j2] = p;
                sum += p;
            }
            mrow[t] = rm;
            lrow[t] = lrow[t] * al + sum;
            arow[t] = al;
        }
        __syncthreads();

        // PV accumulate
        float al = arow[qi];
        accA.x *= al; accA.y *= al; accA.z *= al; accA.w *= al;
        accB.x *= al; accB.y *= al; accB.z *= al; accB.w *= al;
        #pragma unroll 8
        for (int j2 = 0; j2 < 64; ++j2) {
            float p = S[qi * 66 + j2];        // broadcast within 16-lane group
            float4 vA = *(const float4*)&Vs[j2 * 132 + (c << 2)];
            float4 vB = *(const float4*)&Vs[j2 * 132 + 64 + (c << 2)];
            accA.x = fmaf(p, vA.x, accA.x);
            accA.y = fmaf(p, vA.y, accA.y);
            accA.z = fmaf(p, vA.z, accA.z);
            accA.w = fmaf(p, vA.w, accA.w);
            accB.x = fmaf(p, vB.x, accB.x);
            accB.y = fmaf(p, vB.y, accB.y);
            accB.z = fmaf(p, vB.z, accB.z);
            accB.w = fmaf(p, vB.w, accB.w);
        }
    }

    const float inv = 1.0f / lrow[qi];
    float* orow = AO + ((size_t)bb * Tc + tq) * Ec + (h << 7);
    float4 oA = { accA.x * inv, accA.y * inv, accA.z * inv, accA.w * inv };
    float4 oB = { accB.x * inv, accB.y * inv, accB.z * inv, accB.w * inv };
    *(float4*)&orow[(c << 2)]      = oA;
    *(float4*)&orow[64 + (c << 2)] = oB;
}

// ---------------------------------------------------------------------------
// Launch
// ---------------------------------------------------------------------------
extern "C" void kernel_launch(void* const* d_in, const int* in_sizes, int n_in,
                              void* d_out, int out_size, void* d_ws, size_t ws_size,
                              hipStream_t stream)
{
    const float* x    = (const float*)d_in[0];
    const int*  amask = (const int*)  d_in[1];
    const float* Wq   = (const float*)d_in[2];
    const float* bq   = (const float*)d_in[3];
    const float* Wk   = (const float*)d_in[4];
    const float* bk   = (const float*)d_in[5];
    const float* Wv   = (const float*)d_in[6];
    const float* bv   = (const float*)d_in[7];
    const float* Wo   = (const float*)d_in[8];
    const float* bo   = (const float*)d_in[9];
    float* out = (float*)d_out;

    const size_t nQ2d  = (size_t)Bc * Tc * Ec;          // 16,777,216
    const size_t nKV2d = (size_t)Bc * Tc * KVEc;        //  4,194,304
    const size_t nRo   = (size_t)Bc * NKVc * Tc * HDc;  //  4,194,304

    // Workspace layout (floats): [Q2d][Kro][Vro][AO]; K2d/V2d overlay AO
    // (they are consumed by rope before attention writes AO). Total 167.8 MB.
    float* Q2d = (float*)d_ws;
    float* Kro = Q2d + nQ2d;
    float* Vro = Kro + nRo;
    float* AO  = Vro + nRo;
    float* K2d = AO;            // transient
    float* V2d = AO + nKV2d;    // transient

    const int M = Bc * Tc;      // 8192
    dim3 blk(256);

    gemm_bias_f32<<<dim3(M / 64, Ec / 64),   blk, 0, stream>>>(x, Wq, bq, Q2d, M, Ec,   Ec);
    gemm_bias_f32<<<dim3(M / 64, KVEc / 64), blk, 0, stream>>>(x, Wk, bk, K2d, M, KVEc, Ec);
    gemm_bias_f32<<<dim3(M / 64, KVEc / 64), blk, 0, stream>>>(x, Wv, bv, V2d, M, KVEc, Ec);

    const int ropeN = Bc * NKVc * Tc * 64;  // 2,097,152 threads
    rope_remap<<<ropeN / 256, blk, 0, stream>>>(K2d, Kro);
    rope_remap<<<ropeN / 256, blk, 0, stream>>>(V2d, Vro);

    attn_f32<<<dim3(Tc / 16, NHc, Bc), blk, 0, stream>>>(Q2d, Kro, Vro, amask, AO);

    gemm_bias_f32<<<dim3(M / 64, Ec / 64), blk, 0, stream>>>(AO, Wo, bo, out, M, Ec, Ec);
}

// Round 2
// 3331.854 us; speedup vs baseline: 2.0823x; 2.0823x over previous
//
#include <hip/hip_runtime.h>
#include <math.h>

// Problem constants (B,T,E)=(4,2048,2048), NH=16, NKV=4, HD=128
constexpr int Bc   = 4;
constexpr int Tc   = 2048;
constexpr int Ec   = 2048;
constexpr int NHc  = 16;
constexpr int NKVc = 4;
constexpr int HDc  = 128;
constexpr int KVEc = NKVc * HDc; // 512

typedef __attribute__((ext_vector_type(8))) short bf16x8;
typedef __attribute__((ext_vector_type(4))) short short4v;
typedef __attribute__((ext_vector_type(4))) float f32x4;

__device__ inline short f2bf(float f) {           // round-to-nearest-even
    union { float f; unsigned u; } v; v.f = f;
    unsigned r = v.u + 0x7FFF + ((v.u >> 16) & 1);
    return (short)(r >> 16);
}
__device__ inline float bf2f(short s) {
    union { unsigned u; float f; } v; v.u = ((unsigned)(unsigned short)s) << 16;
    return v.f;
}

// ---------------------------------------------------------------------------
// fp32 GEMM: C[M,N] = A[M,K] @ W[K,N] + bias[N]   (unchanged from round 1)
// ---------------------------------------------------------------------------
__global__ __launch_bounds__(256)
void gemm_bias_f32(const float* __restrict__ A, const float* __restrict__ W,
                   const float* __restrict__ bias, float* __restrict__ C,
                   int M, int N, int K)
{
    __shared__ float As[16][64];
    __shared__ float Ws[16][64];
    const int t  = threadIdx.x;
    const int bm = blockIdx.x * 64;
    const int bn = blockIdx.y * 64;
    const int tx = t & 15;
    const int ty = t >> 4;
    const int rowA = t >> 2;
    const int kcA  = (t & 3) << 2;
    const int rowW = t >> 4;
    const int colW = (t & 15) << 2;

    float acc[4][4] = {};

    for (int k0 = 0; k0 < K; k0 += 16) {
        float4 a4 = *(const float4*)(A + (size_t)(bm + rowA) * K + (k0 + kcA));
        float4 w4 = *(const float4*)(W + (size_t)(k0 + rowW) * N + (bn + colW));
        __syncthreads();
        As[kcA + 0][rowA] = a4.x;
        As[kcA + 1][rowA] = a4.y;
        As[kcA + 2][rowA] = a4.z;
        As[kcA + 3][rowA] = a4.w;
        *(float4*)&Ws[rowW][colW] = w4;
        __syncthreads();
        #pragma unroll
        for (int k = 0; k < 16; ++k) {
            float4 av = *(const float4*)&As[k][ty << 2];
            float4 wv = *(const float4*)&Ws[k][tx << 2];
            float a0[4] = {av.x, av.y, av.z, av.w};
            float w0[4] = {wv.x, wv.y, wv.z, wv.w};
            #pragma unroll
            for (int i = 0; i < 4; ++i)
                #pragma unroll
                for (int j = 0; j < 4; ++j)
                    acc[i][j] = fmaf(a0[i], w0[j], acc[i][j]);
        }
    }
    const int colb = bn + (tx << 2);
    float4 bv = *(const float4*)(bias + colb);
    #pragma unroll
    for (int i = 0; i < 4; ++i) {
        float4 o = { acc[i][0] + bv.x, acc[i][1] + bv.y,
                     acc[i][2] + bv.z, acc[i][3] + bv.w };
        *(float4*)(C + (size_t)(bm + (ty << 2) + i) * N + colb) = o;
    }
}

// ---------------------------------------------------------------------------
// RoPE + remap (unchanged from round 1)
// ---------------------------------------------------------------------------
__global__ __launch_bounds__(256)
void rope_remap(const float* __restrict__ X2d, float* __restrict__ Y)
{
    const int idx = blockIdx.x * 256 + threadIdx.x;
    const int j  = idx & 63;
    const int tk = (idx >> 6) & (Tc - 1);
    const int kh = (idx >> 17) & (NKVc - 1);
    const int bb = idx >> 19;
    const int row = (kh << 9) + (tk >> 2);
    const int col = ((tk & 3) << 7) + (j << 1);
    const float* src = X2d + ((size_t)bb * Tc + row) * KVEc + col;
    const float a = src[0];
    const float b = src[1];
    const float theta = powf(10000.0f, -(float)j * (1.0f / 64.0f));
    const float ang = (float)tk * theta;
    float s, c;
    sincosf(ang, &s, &c);
    float* dst = Y + (((size_t)bb * NKVc + kh) * Tc + tk) * HDc + (j << 1);
    dst[0] = a * c - b * s;
    dst[1] = a * s + b * c;
}

// ---------------------------------------------------------------------------
// MFMA flash attention.
// Block: 256 threads = 4 waves; wave w owns q-rows [qb*64 + w*16, +16).
// K-tiles of 64 keys. QK^T via split-bf16 (hi/lo, 3 MFMAs) for fp32-fidelity
// scores; PV via plain bf16. Online softmax state in registers.
// MFMA 16x16x32 layouts (m89/m91-verified):
//   A: lane holds m=L&15,  k=(L>>4)*8+j
//   B: lane holds n=L&15,  k=(L>>4)*8+j
//   C: lane holds col=L&15, row=(L>>4)*4+reg
// ---------------------------------------------------------------------------
__global__ __launch_bounds__(256, 2)
void attn_mfma(const float* __restrict__ Q2d, const float* __restrict__ Kro,
               const float* __restrict__ Vro, const int* __restrict__ mask,
               float* __restrict__ AO)
{
    constexpr int SK = 136;  // Khi/Klo row stride (shorts): 128+8, b128-aligned
    constexpr int SV = 72;   // Vt row stride (shorts): 64+8, b128-aligned
    constexpr int SP = 72;   // Ps row stride (shorts)
    __shared__ short Khi[64 * SK];   // [key][dim] bf16 hi
    __shared__ short Klo[64 * SK];   // [key][dim] bf16 lo
    __shared__ short Vt [128 * SV];  // [dim][key] bf16 (transposed)
    __shared__ short Ps [64 * SP];   // [q][key]   bf16 probabilities

    const int qb = blockIdx.x;   // 0..31
    const int h  = blockIdx.y;   // 0..15
    const int bb = blockIdx.z;   // 0..3
    const int t  = threadIdx.x;
    const int w    = t >> 6;     // wave 0..3
    const int L    = t & 63;
    const int l16  = L & 15;
    const int quad = L >> 4;     // 0..3
    const int kh   = h & (NKVc - 1);   // jnp.tile: head h uses kv-head h%4
    const int tq0  = qb * 64 + w * 16; // wave's first query row

    // ---- Q fragments (hi/lo split), loaded once from global ----
    // q[b,h,tq,d] = Q2d[b, h*128 + tq/16, 128*(tq%16) + d]; tq = tq0 + l16
    // => Q2d row = h*128 + qb*4 + w (constant per wave), col = 128*l16 + d
    bf16x8 qhi[4], qlo[4];
    {
        const float* qrow = Q2d +
            ((size_t)(bb * Tc + h * HDc + qb * 4 + w)) * Ec + 128 * l16;
        #pragma unroll
        for (int kc = 0; kc < 4; ++kc) {
            const float* p = qrow + kc * 32 + quad * 8;
            #pragma unroll
            for (int j = 0; j < 8; ++j) {
                float f = p[j];
                short hi = f2bf(f);
                qhi[kc][j] = hi;
                qlo[kc][j] = f2bf(f - bf2f(hi));
            }
        }
    }

    float m_r[4], l_r[4];
    #pragma unroll
    for (int r = 0; r < 4; ++r) { m_r[r] = -INFINITY; l_r[r] = 0.0f; }
    f32x4 o[8];
    #pragma unroll
    for (int nc = 0; nc < 8; ++nc) o[nc] = (f32x4){0, 0, 0, 0};

    const float* kbase = Kro + ((size_t)(bb * NKVc + kh)) * Tc * HDc;
    const float* vbase = Vro + ((size_t)(bb * NKVc + kh)) * Tc * HDc;
    const int*   mbase = mask + (size_t)bb * Tc * Tc;
    const float  scale = 11.313708498984761f;  // sqrt(128)

    const int vd    = t & 127;   // dim this thread transposes for Vt
    const int khalf = t >> 7;

    for (int kt = 0; kt < Tc / 64; ++kt) {
        // mask values for this tile (independent of LDS; issue early)
        int mv[4][4];
        {
            const int* mcol = mbase + (size_t)kt * 64 + l16;
            #pragma unroll
            for (int r = 0; r < 4; ++r) {
                const int* mrow = mcol + (size_t)(tq0 + quad * 4 + r) * Tc;
                #pragma unroll
                for (int nt = 0; nt < 4; ++nt) mv[nt][r] = mrow[nt * 16];
            }
        }

        __syncthreads();   // previous tile's Khi/Klo/Vt reads complete

        // ---- stage K tile as bf16 hi/lo: [key][dim] ----
        const float* kg = kbase + (size_t)kt * 64 * HDc;
        #pragma unroll
        for (int it = 0; it < 8; ++it) {
            int e  = it * 256 + t;
            int kr = e >> 5;
            int c4 = (e & 31) << 2;
            float4 kv = *(const float4*)(kg + (size_t)kr * HDc + c4);
            float fv[4] = {kv.x, kv.y, kv.z, kv.w};
            short4v hi, lo;
            #pragma unroll
            for (int i = 0; i < 4; ++i) {
                hi[i] = f2bf(fv[i]);
                lo[i] = f2bf(fv[i] - bf2f(hi[i]));
            }
            *(short4v*)&Khi[kr * SK + c4] = hi;
            *(short4v*)&Klo[kr * SK + c4] = lo;
        }
        // ---- stage V tile transposed bf16: Vt[dim][key] ----
        const float* vg = vbase + (size_t)kt * 64 * HDc;
        #pragma unroll
        for (int it = 0; it < 8; ++it) {
            int k0 = ((khalf + 2 * it) << 2);   // 0,4,...,60
            short4v vv;
            #pragma unroll
            for (int i = 0; i < 4; ++i)
                vv[i] = f2bf(vg[(size_t)(k0 + i) * HDc + vd]);
            *(short4v*)&Vt[vd * SV + k0] = vv;
        }
        __syncthreads();

        // ---- QK^T: S(16q x 64k) = Q . K^T, split-bf16 (3 MFMA) ----
        f32x4 s[4];
        #pragma unroll
        for (int nt = 0; nt < 4; ++nt) {
            f32x4 acc = (f32x4){0, 0, 0, 0};
            #pragma unroll
            for (int kc = 0; kc < 4; ++kc) {
                const int ko = (nt * 16 + l16) * SK + kc * 32 + quad * 8;
                bf16x8 khiF = *(const bf16x8*)&Khi[ko];
                bf16x8 kloF = *(const bf16x8*)&Klo[ko];
                acc = __builtin_amdgcn_mfma_f32_16x16x32_bf16(qhi[kc], khiF, acc, 0, 0, 0);
                acc = __builtin_amdgcn_mfma_f32_16x16x32_bf16(qlo[kc], khiF, acc, 0, 0, 0);
                acc = __builtin_amdgcn_mfma_f32_16x16x32_bf16(qhi[kc], kloF, acc, 0, 0, 0);
            }
            s[nt] = acc;
        }

        // ---- scale + mask (mask==0 -> 1e-9, else s*sqrt(128)) ----
        #pragma unroll
        for (int nt = 0; nt < 4; ++nt)
            #pragma unroll
            for (int r = 0; r < 4; ++r)
                s[nt][r] = (mv[nt][r] == 0) ? 1e-9f : s[nt][r] * scale;

        // ---- online softmax (rows live in 16-lane groups) ----
        float mt[4];
        #pragma unroll
        for (int r = 0; r < 4; ++r)
            mt[r] = fmaxf(fmaxf(s[0][r], s[1][r]), fmaxf(s[2][r], s[3][r]));
        #pragma unroll
        for (int off = 1; off < 16; off <<= 1)
            #pragma unroll
            for (int r = 0; r < 4; ++r)
                mt[r] = fmaxf(mt[r], __shfl_xor(mt[r], off));

        float al[4];
        #pragma unroll
        for (int r = 0; r < 4; ++r) {
            float mn = fmaxf(m_r[r], mt[r]);
            al[r] = __expf(m_r[r] - mn);   // exp(-inf)=0 on first tile
            m_r[r] = mn;
        }
        float rs[4] = {0, 0, 0, 0};
        #pragma unroll
        for (int nt = 0; nt < 4; ++nt)
            #pragma unroll
            for (int r = 0; r < 4; ++r) {
                float p = __expf(s[nt][r] - m_r[r]);
                s[nt][r] = p;
                rs[r] += p;
            }
        #pragma unroll
        for (int off = 1; off < 16; off <<= 1)
            #pragma unroll
            for (int r = 0; r < 4; ++r)
                rs[r] += __shfl_xor(rs[r], off);
        #pragma unroll
        for (int r = 0; r < 4; ++r) l_r[r] = l_r[r] * al[r] + rs[r];
        #pragma unroll
        for (int nc = 0; nc < 8; ++nc)
            #pragma unroll
            for (int r = 0; r < 4; ++r)
                o[nc][r] *= al[r];

        // ---- P: C-layout -> LDS (bf16) -> A-layout (wave-private rows) ----
        #pragma unroll
        for (int nt = 0; nt < 4; ++nt)
            #pragma unroll
            for (int r = 0; r < 4; ++r)
                Ps[(w * 16 + quad * 4 + r) * SP + nt * 16 + l16] = f2bf(s[nt][r]);

        bf16x8 a0 = *(const bf16x8*)&Ps[(w * 16 + l16) * SP + quad * 8];
        bf16x8 a1 = *(const bf16x8*)&Ps[(w * 16 + l16) * SP + 32 + quad * 8];

        // ---- PV: O(16q x 128d) += P . V ----
        #pragma unroll
        for (int nc = 0; nc < 8; ++nc) {
            const int vo = (nc * 16 + l16) * SV + quad * 8;
            bf16x8 b0 = *(const bf16x8*)&Vt[vo];
            bf16x8 b1 = *(const bf16x8*)&Vt[vo + 32];
            o[nc] = __builtin_amdgcn_mfma_f32_16x16x32_bf16(a0, b0, o[nc], 0, 0, 0);
            o[nc] = __builtin_amdgcn_mfma_f32_16x16x32_bf16(a1, b1, o[nc], 0, 0, 0);
        }
    }

    // ---- epilogue: normalize and store AO[b][tq][h*128 + d] ----
    float inv[4];
    #pragma unroll
    for (int r = 0; r < 4; ++r) inv[r] = 1.0f / l_r[r];
    #pragma unroll
    for (int r = 0; r < 4; ++r) {
        float* orow = AO + ((size_t)(bb * Tc + tq0 + quad * 4 + r)) * Ec
                         + h * HDc + l16;
        #pragma unroll
        for (int nc = 0; nc < 8; ++nc)
            orow[nc * 16] = o[nc][r] * inv[r];
    }
}

// ---------------------------------------------------------------------------
// Launch
// ---------------------------------------------------------------------------
extern "C" void kernel_launch(void* const* d_in, const int* in_sizes, int n_in,
                              void* d_out, int out_size, void* d_ws, size_t ws_size,
                              hipStream_t stream)
{
    const float* x    = (const float*)d_in[0];
    const int*  amask = (const int*)  d_in[1];
    const float* Wq   = (const float*)d_in[2];
    const float* bq   = (const float*)d_in[3];
    const float* Wk   = (const float*)d_in[4];
    const float* bk   = (const float*)d_in[5];
    const float* Wv   = (const float*)d_in[6];
    const float* bv   = (const float*)d_in[7];
    const float* Wo   = (const float*)d_in[8];
    const float* bo   = (const float*)d_in[9];
    float* out = (float*)d_out;

    const size_t nQ2d  = (size_t)Bc * Tc * Ec;
    const size_t nKV2d = (size_t)Bc * Tc * KVEc;
    const size_t nRo   = (size_t)Bc * NKVc * Tc * HDc;

    float* Q2d = (float*)d_ws;
    float* Kro = Q2d + nQ2d;
    float* Vro = Kro + nRo;
    float* AO  = Vro + nRo;
    float* K2d = AO;            // transient (consumed by rope before AO write)
    float* V2d = AO + nKV2d;

    const int M = Bc * Tc;      // 8192
    dim3 blk(256);

    gemm_bias_f32<<<dim3(M / 64, Ec / 64),   blk, 0, stream>>>(x, Wq, bq, Q2d, M, Ec,   Ec);
    gemm_bias_f32<<<dim3(M / 64, KVEc / 64), blk, 0, stream>>>(x, Wk, bk, K2d, M, KVEc, Ec);
    gemm_bias_f32<<<dim3(M / 64, KVEc / 64), blk, 0, stream>>>(x, Wv, bv, V2d, M, KVEc, Ec);

    const int ropeN = Bc * NKVc * Tc * 64;
    rope_remap<<<ropeN / 256, blk, 0, stream>>>(K2d, Kro);
    rope_remap<<<ropeN / 256, blk, 0, stream>>>(V2d, Vro);

    attn_mfma<<<dim3(Tc / 64, NHc, Bc), blk, 0, stream>>>(Q2d, Kro, Vro, amask, AO);

    gemm_bias_f32<<<dim3(M / 64, Ec / 64), blk, 0, stream>>>(AO, Wo, bo, out, M, Ec, Ec);
}

// Round 3
// 1114.280 us; speedup vs baseline: 6.2263x; 2.9901x over previous
//
#include <hip/hip_runtime.h>
#include <math.h>

// Problem constants (B,T,E)=(4,2048,2048), NH=16, NKV=4, HD=128
constexpr int Bc   = 4;
constexpr int Tc   = 2048;
constexpr int Ec   = 2048;
constexpr int NHc  = 16;
constexpr int NKVc = 4;
constexpr int HDc  = 128;
constexpr int KVEc = NKVc * HDc; // 512

typedef __attribute__((ext_vector_type(8))) short bf16x8;
typedef __attribute__((ext_vector_type(4))) short short4v;
typedef __attribute__((ext_vector_type(4))) float f32x4;

__device__ __forceinline__ short f2bf(float f) {   // round-to-nearest-even
    union { float f; unsigned u; } v; v.f = f;
    unsigned r = v.u + 0x7FFF + ((v.u >> 16) & 1);
    return (short)(r >> 16);
}
__device__ __forceinline__ float bf2f(short s) {
    union { unsigned u; float f; } v; v.u = ((unsigned)(unsigned short)s) << 16;
    return v.f;
}
// async global->LDS, 16B per lane; lptr must be wave-uniform (dest = base + lane*16)
__device__ __forceinline__ void gload16(const void* g, void* l) {
    __builtin_amdgcn_global_load_lds(
        (const __attribute__((address_space(1))) unsigned*)g,
        (__attribute__((address_space(3))) unsigned*)l, 16, 0, 0);
}

// ---------------------------------------------------------------------------
// Prep: x fp32 -> hi/lo bf16 (same layout)
// ---------------------------------------------------------------------------
__global__ __launch_bounds__(256)
void convert_split(const float* __restrict__ X, short* __restrict__ Xhi,
                   short* __restrict__ Xlo)
{
    int i = blockIdx.x * 256 + threadIdx.x;    // float4 index
    float4 v = ((const float4*)X)[i];
    float fv[4] = {v.x, v.y, v.z, v.w};
    short4v hi, lo;
    #pragma unroll
    for (int j = 0; j < 4; ++j) {
        hi[j] = f2bf(fv[j]);
        lo[j] = f2bf(fv[j] - bf2f(hi[j]));
    }
    ((short4v*)Xhi)[i] = hi;
    ((short4v*)Xlo)[i] = lo;
}

// ---------------------------------------------------------------------------
// Prep: W [K][N] fp32 -> WT hi (and optional lo) [N][K] bf16
// ---------------------------------------------------------------------------
__global__ __launch_bounds__(256)
void transpose_split(const float* __restrict__ W, short* __restrict__ WThi,
                     short* __restrict__ WTlo, int K, int N)
{
    __shared__ float Ls[32][33];
    const int k0 = blockIdx.x * 32, n0 = blockIdx.y * 32;
    const int t = threadIdx.x;
    const int r = t >> 3, c4 = (t & 7) << 2;
    float4 v = *(const float4*)(W + (size_t)(k0 + r) * N + n0 + c4);
    Ls[r][c4 + 0] = v.x; Ls[r][c4 + 1] = v.y;
    Ls[r][c4 + 2] = v.z; Ls[r][c4 + 3] = v.w;
    __syncthreads();
    short4v hi, lo;
    #pragma unroll
    for (int i = 0; i < 4; ++i) {
        float f = Ls[c4 + i][r];
        hi[i] = f2bf(f);
        lo[i] = f2bf(f - bf2f(hi[i]));
    }
    *(short4v*)(WThi + (size_t)(n0 + r) * K + k0 + c4) = hi;
    if (WTlo) *(short4v*)(WTlo + (size_t)(n0 + r) * K + k0 + c4) = lo;
}

// ---------------------------------------------------------------------------
// MFMA GEMM: C[M][N] = A[M][K] @ B[N][K]^T + bias  (A,B bf16; C fp32)
// SPLIT: A=Ahi+Alo, B=Bhi+Blo, 3-MFMA products (fp32-fidelity).
// 128x128 tile, BK=32, 4 waves (2x2 of 64x64), global_load_lds staging,
// XOR-swizzled LDS chunks (16B units): within 16-row group,
//   chunk(row m, kchunk q) at position m*4 + ((q + (m>>2)) & 3)  -> 2-way reads.
// ---------------------------------------------------------------------------
template <bool SPLIT>
__global__ __launch_bounds__(256, 2)
void gemm_mfma(const short* __restrict__ Ahi, const short* __restrict__ Alo,
               const short* __restrict__ Bhi, const short* __restrict__ Blo,
               const float* __restrict__ bias, float* __restrict__ C,
               int M, int N, int K)
{
    __shared__ short AsH[128 * 32];
    __shared__ short BsH[128 * 32];
    __shared__ short AsL[SPLIT ? 128 * 32 : 8];
    __shared__ short BsL[SPLIT ? 128 * 32 : 8];

    const int t = threadIdx.x;
    const int w = t >> 6, L = t & 63;
    const int l16 = L & 15, quad = L >> 4;
    const int wr = w >> 1, wc = w & 1;
    const int bm = blockIdx.x * 128, bn = blockIdx.y * 128;

    // staging decode: lane L stages chunk position L of its wave-load
    const int sm = L >> 2;                        // row in 16-row group
    const int sq = ((L & 3) - (sm >> 2)) & 3;     // k-chunk in row
    const int scol = sq * 8;                      // short offset in row

    f32x4 acc[4][4];
    #pragma unroll
    for (int mi = 0; mi < 4; ++mi)
        #pragma unroll
        for (int ni = 0; ni < 4; ++ni) acc[mi][ni] = (f32x4){0, 0, 0, 0};

    // fragment chunk indices (loop-invariant)
    const int fxor = (quad + (l16 >> 2)) & 3;

    for (int k0 = 0; k0 < K; k0 += 32) {
        __syncthreads();   // previous iter's ds_reads complete
        #pragma unroll
        for (int i = 0; i < 2; ++i) {
            const int wl = w * 2 + i;
            const size_t ra = (size_t)(bm + wl * 16 + sm) * K + k0 + scol;
            const size_t rb = (size_t)(bn + wl * 16 + sm) * K + k0 + scol;
            gload16(Ahi + ra, &AsH[wl * 512]);
            gload16(Bhi + rb, &BsH[wl * 512]);
            if (SPLIT) {
                gload16(Alo + ra, &AsL[wl * 512]);
                gload16(Blo + rb, &BsL[wl * 512]);
            }
        }
        __syncthreads();   // loads drained (vmcnt(0) before barrier)

        bf16x8 ah[4], bh[4], al[4], bl[4];
        #pragma unroll
        for (int mi = 0; mi < 4; ++mi) {
            const int ch = ((wr * 4 + mi) * 64 + l16 * 4 + fxor) * 8;
            ah[mi] = *(const bf16x8*)&AsH[ch];
            if (SPLIT) al[mi] = *(const bf16x8*)&AsL[ch];
        }
        #pragma unroll
        for (int ni = 0; ni < 4; ++ni) {
            const int ch = ((wc * 4 + ni) * 64 + l16 * 4 + fxor) * 8;
            bh[ni] = *(const bf16x8*)&BsH[ch];
            if (SPLIT) bl[ni] = *(const bf16x8*)&BsL[ch];
        }
        #pragma unroll
        for (int mi = 0; mi < 4; ++mi)
            #pragma unroll
            for (int ni = 0; ni < 4; ++ni) {
                acc[mi][ni] = __builtin_amdgcn_mfma_f32_16x16x32_bf16(
                    ah[mi], bh[ni], acc[mi][ni], 0, 0, 0);
                if (SPLIT) {
                    acc[mi][ni] = __builtin_amdgcn_mfma_f32_16x16x32_bf16(
                        al[mi], bh[ni], acc[mi][ni], 0, 0, 0);
                    acc[mi][ni] = __builtin_amdgcn_mfma_f32_16x16x32_bf16(
                        ah[mi], bl[ni], acc[mi][ni], 0, 0, 0);
                }
            }
    }

    #pragma unroll
    for (int ni = 0; ni < 4; ++ni) {
        const int col = bn + wc * 64 + ni * 16 + l16;
        const float bv = bias[col];
        #pragma unroll
        for (int mi = 0; mi < 4; ++mi) {
            #pragma unroll
            for (int r = 0; r < 4; ++r) {
                const int row = bm + wr * 64 + mi * 16 + quad * 4 + r;
                C[(size_t)row * N + col] = acc[mi][ni][r] + bv;
            }
        }
    }
}

// ---------------------------------------------------------------------------
// RoPE for K: fp32 K2d (B,T,512) -> Khi/Klo bf16 (B,NKV,T,HD)
// ---------------------------------------------------------------------------
__global__ __launch_bounds__(256)
void rope_k(const float* __restrict__ X2d, short* __restrict__ Khi,
            short* __restrict__ Klo)
{
    const int idx = blockIdx.x * 256 + threadIdx.x;
    const int j  = idx & 63;
    const int tk = (idx >> 6) & (Tc - 1);
    const int kh = (idx >> 17) & (NKVc - 1);
    const int bb = idx >> 19;
    const int row = (kh << 9) + (tk >> 2);
    const int col = ((tk & 3) << 7) + (j << 1);
    const float* src = X2d + ((size_t)bb * Tc + row) * KVEc + col;
    const float a = src[0];
    const float b = src[1];
    const float theta = powf(10000.0f, -(float)j * (1.0f / 64.0f));
    const float ang = (float)tk * theta;
    float s, c;
    sincosf(ang, &s, &c);
    const float r0 = a * c - b * s;
    const float r1 = a * s + b * c;
    const size_t off = (((size_t)bb * NKVc + kh) * Tc + tk) * HDc + (j << 1);
    short h0 = f2bf(r0), h1 = f2bf(r1);
    Khi[off]     = h0;  Klo[off]     = f2bf(r0 - bf2f(h0));
    Khi[off + 1] = h1;  Klo[off + 1] = f2bf(r1 - bf2f(h1));
}

// ---------------------------------------------------------------------------
// RoPE for V fused with transpose: fp32 V2d (B,T,512) -> Vt bf16 (B,NKV,HD,T)
// Block handles (b, kh, 32 tk) = contiguous 8x512 fp32 region of V2d.
// ---------------------------------------------------------------------------
__global__ __launch_bounds__(256)
void rope_v_t(const float* __restrict__ V2d, short* __restrict__ Vt)
{
    __shared__ short Ls[128][40];   // [d][tk_local], 80B rows (16B-aligned)
    const int g  = blockIdx.x;      // tk group of 32 (0..63)
    const int kh = blockIdx.y;
    const int bb = blockIdx.z;
    const int t  = threadIdx.x;

    const float* src = V2d + ((size_t)bb * Tc + (kh << 9) + (g << 3)) * KVEc;
    #pragma unroll
    for (int i = 0; i < 4; ++i) {
        int e = i * 256 + t;             // 0..1023 float4s
        float4 v = ((const float4*)src)[e];
        int row = e >> 7;                // 0..7
        int col = (e & 127) << 2;        // 0..508
        int tkl = (row << 2) + (col >> 7);
        int d0  = col & 127;
        int tk  = (g << 5) + tkl;
        float fv[4] = {v.x, v.y, v.z, v.w};
        #pragma unroll
        for (int p = 0; p < 2; ++p) {
            int j = (d0 >> 1) + p;
            float theta = powf(10000.0f, -(float)j * (1.0f / 64.0f));
            float ang = (float)tk * theta;
            float s, c;
            sincosf(ang, &s, &c);
            float a = fv[2 * p], b = fv[2 * p + 1];
            Ls[d0 + 2 * p    ][tkl] = f2bf(a * c - b * s);
            Ls[d0 + 2 * p + 1][tkl] = f2bf(a * s + b * c);
        }
    }
    __syncthreads();
    const int d = t >> 1;
    const int h16 = (t & 1) << 4;
    short* dst = Vt + (((size_t)bb * NKVc + kh) * HDc + d) * Tc + (g << 5) + h16;
    bf16x8 o0 = *(const bf16x8*)&Ls[d][h16];
    bf16x8 o1 = *(const bf16x8*)&Ls[d][h16 + 8];
    *(bf16x8*)dst = o0;
    *(bf16x8*)(dst + 8) = o1;
}

// ---------------------------------------------------------------------------
// MFMA flash attention. 4 waves x 16 q-rows; K-tiles of 64 keys.
// K (hi/lo) and V^T staged via global_load_lds with XOR-swizzled chunks:
//  K tile 64x128 shorts (16 chunks/row): chunk(row,c) at
//     (row>>2)*64 + (row&3)*16 + ((c + (row&15)) & 15)
//  V tile 128x64 shorts (8 chunks/row): chunk(row,c) at
//     (row>>3)*64 + (row&7)*8 + ((c + (row&7)) & 7)
// Both give 2-way (free) bank aliasing on fragment ds_read_b128.
// ---------------------------------------------------------------------------
__global__ __launch_bounds__(256, 2)
void attn_mfma(const float* __restrict__ Q2d, const short* __restrict__ Khi_g,
               const short* __restrict__ Klo_g, const short* __restrict__ Vt_g,
               const int* __restrict__ mask, short* __restrict__ AObf)
{
    constexpr int SP = 72;
    __shared__ short KhiS[64 * 128];
    __shared__ short KloS[64 * 128];
    __shared__ short VtS [128 * 64];
    __shared__ short Ps  [64 * SP];

    const int qb = blockIdx.x;   // 0..31
    const int h  = blockIdx.y;   // 0..15
    const int bb = blockIdx.z;   // 0..3
    const int t  = threadIdx.x;
    const int w    = t >> 6;
    const int L    = t & 63;
    const int l16  = L & 15;
    const int quad = L >> 4;
    const int kh   = h & (NKVc - 1);     // jnp.tile: head h -> kv-head h%4
    const int tq0  = qb * 64 + w * 16;

    // ---- Q fragments (hi/lo split) from fp32 Q2d, loaded once ----
    bf16x8 qhi[4], qlo[4];
    {
        const float* qrow = Q2d +
            ((size_t)(bb * Tc + h * HDc + qb * 4 + w)) * Ec + 128 * l16;
        #pragma unroll
        for (int kc = 0; kc < 4; ++kc) {
            const float* p = qrow + kc * 32 + quad * 8;
            #pragma unroll
            for (int j = 0; j < 8; ++j) {
                float f = p[j];
                short hi = f2bf(f);
                qhi[kc][j] = hi;
                qlo[kc][j] = f2bf(f - bf2f(hi));
            }
        }
    }

    float m_r[4], l_r[4];
    #pragma unroll
    for (int r = 0; r < 4; ++r) { m_r[r] = -INFINITY; l_r[r] = 0.0f; }
    f32x4 o[8];
    #pragma unroll
    for (int nc = 0; nc < 8; ++nc) o[nc] = (f32x4){0, 0, 0, 0};

    const short* kbh = Khi_g + ((size_t)(bb * NKVc + kh)) * Tc * HDc;
    const short* kbl = Klo_g + ((size_t)(bb * NKVc + kh)) * Tc * HDc;
    const short* vb  = Vt_g  + ((size_t)(bb * NKVc + kh)) * HDc * Tc;
    const int*   mbase = mask + (size_t)bb * Tc * Tc;
    const float  scale = 11.313708498984761f;  // sqrt(128)

    // staging lane decode
    const int km   = L >> 4;              // K: row-in-4-group
    const int kpos = L & 15;
    const int vm   = L >> 3;              // V: row-in-8-group (== row&7)
    const int vc   = ((L & 7) - vm) & 7;  // V: chunk-in-row

    for (int kt = 0; kt < Tc / 64; ++kt) {
        // mask values (global, independent of LDS)
        int mv[4][4];
        {
            const int* mcol = mbase + (size_t)kt * 64 + l16;
            #pragma unroll
            for (int r = 0; r < 4; ++r) {
                const int* mrow = mcol + (size_t)(tq0 + quad * 4 + r) * Tc;
                #pragma unroll
                for (int nt = 0; nt < 4; ++nt) mv[nt][r] = mrow[nt * 16];
            }
        }

        __syncthreads();   // previous tile's LDS reads complete

        // ---- stage K hi/lo (16 wave-loads each of 4 rows) + V^T (8 rows) ----
        #pragma unroll
        for (int i = 0; i < 4; ++i) {
            const int wl = w * 4 + i;
            const int krow = wl * 4 + km;
            const int kc_ = (kpos - (krow & 15)) & 15;
            const size_t go = (size_t)(kt * 64 + krow) * HDc + kc_ * 8;
            gload16(kbh + go, &KhiS[wl * 512]);
            gload16(kbl + go, &KloS[wl * 512]);
            const int vrow = wl * 8 + vm;
            gload16(vb + (size_t)vrow * Tc + kt * 64 + vc * 8, &VtS[wl * 512]);
        }
        __syncthreads();   // loads drained

        // ---- QK^T: S(16q x 64k), split-bf16 (3 MFMA) ----
        f32x4 s[4];
        #pragma unroll
        for (int nt = 0; nt < 4; ++nt) {
            f32x4 acc = (f32x4){0, 0, 0, 0};
            #pragma unroll
            for (int kc = 0; kc < 4; ++kc) {
                const int ch = (((nt * 4 + (l16 >> 2)) << 6) + ((l16 & 3) << 4)
                                + ((kc * 4 + quad + l16) & 15)) << 3;
                bf16x8 khiF = *(const bf16x8*)&KhiS[ch];
                bf16x8 kloF = *(const bf16x8*)&KloS[ch];
                acc = __builtin_amdgcn_mfma_f32_16x16x32_bf16(qhi[kc], khiF, acc, 0, 0, 0);
                acc = __builtin_amdgcn_mfma_f32_16x16x32_bf16(qlo[kc], khiF, acc, 0, 0, 0);
                acc = __builtin_amdgcn_mfma_f32_16x16x32_bf16(qhi[kc], kloF, acc, 0, 0, 0);
            }
            s[nt] = acc;
        }

        // ---- scale + mask ----
        #pragma unroll
        for (int nt = 0; nt < 4; ++nt)
            #pragma unroll
            for (int r = 0; r < 4; ++r)
                s[nt][r] = (mv[nt][r] == 0) ? 1e-9f : s[nt][r] * scale;

        // ---- online softmax ----
        float mt[4];
        #pragma unroll
        for (int r = 0; r < 4; ++r)
            mt[r] = fmaxf(fmaxf(s[0][r], s[1][r]), fmaxf(s[2][r], s[3][r]));
        #pragma unroll
        for (int off = 1; off < 16; off <<= 1)
            #pragma unroll
            for (int r = 0; r < 4; ++r)
                mt[r] = fmaxf(mt[r], __shfl_xor(mt[r], off));

        float al[4];
        #pragma unroll
        for (int r = 0; r < 4; ++r) {
            float mn = fmaxf(m_r[r], mt[r]);
            al[r] = __expf(m_r[r] - mn);
            m_r[r] = mn;
        }
        float rs[4] = {0, 0, 0, 0};
        #pragma unroll
        for (int nt = 0; nt < 4; ++nt)
            #pragma unroll
            for (int r = 0; r < 4; ++r) {
                float p = __expf(s[nt][r] - m_r[r]);
                s[nt][r] = p;
                rs[r] += p;
            }
        #pragma unroll
        for (int off = 1; off < 16; off <<= 1)
            #pragma unroll
            for (int r = 0; r < 4; ++r)
                rs[r] += __shfl_xor(rs[r], off);
        #pragma unroll
        for (int r = 0; r < 4; ++r) l_r[r] = l_r[r] * al[r] + rs[r];
        #pragma unroll
        for (int nc = 0; nc < 8; ++nc)
            #pragma unroll
            for (int r = 0; r < 4; ++r)
                o[nc][r] *= al[r];

        // ---- P: C-layout -> LDS -> A-layout (wave-private rows) ----
        #pragma unroll
        for (int nt = 0; nt < 4; ++nt)
            #pragma unroll
            for (int r = 0; r < 4; ++r)
                Ps[(w * 16 + quad * 4 + r) * SP + nt * 16 + l16] = f2bf(s[nt][r]);

        bf16x8 a0 = *(const bf16x8*)&Ps[(w * 16 + l16) * SP + quad * 8];
        bf16x8 a1 = *(const bf16x8*)&Ps[(w * 16 + l16) * SP + 32 + quad * 8];

        // ---- PV: O(16q x 128d) += P . V ----
        #pragma unroll
        for (int nc = 0; nc < 8; ++nc) {
            const int rg = (nc * 2 + (l16 >> 3)) << 6;
            const int rm = l16 & 7;
            const int ch0 = (rg + (rm << 3) + ((quad + rm) & 7)) << 3;
            const int ch1 = (rg + (rm << 3) + ((quad + 4 + rm) & 7)) << 3;
            bf16x8 b0 = *(const bf16x8*)&VtS[ch0];
            bf16x8 b1 = *(const bf16x8*)&VtS[ch1];
            o[nc] = __builtin_amdgcn_mfma_f32_16x16x32_bf16(a0, b0, o[nc], 0, 0, 0);
            o[nc] = __builtin_amdgcn_mfma_f32_16x16x32_bf16(a1, b1, o[nc], 0, 0, 0);
        }
    }

    // ---- epilogue: normalize, store bf16 AO[b][tq][h*128+d] ----
    float inv[4];
    #pragma unroll
    for (int r = 0; r < 4; ++r) inv[r] = 1.0f / l_r[r];
    #pragma unroll
    for (int r = 0; r < 4; ++r) {
        short* orow = AObf + ((size_t)(bb * Tc + tq0 + quad * 4 + r)) * Ec
                           + h * HDc + l16;
        #pragma unroll
        for (int nc = 0; nc < 8; ++nc)
            orow[nc * 16] = f2bf(o[nc][r] * inv[r]);
    }
}

// ---------------------------------------------------------------------------
// Launch
// ---------------------------------------------------------------------------
extern "C" void kernel_launch(void* const* d_in, const int* in_sizes, int n_in,
                              void* d_out, int out_size, void* d_ws, size_t ws_size,
                              hipStream_t stream)
{
    const float* x    = (const float*)d_in[0];
    const int*  amask = (const int*)  d_in[1];
    const float* Wq   = (const float*)d_in[2];
    const float* bq   = (const float*)d_in[3];
    const float* Wk   = (const float*)d_in[4];
    const float* bk   = (const float*)d_in[5];
    const float* Wv   = (const float*)d_in[6];
    const float* bv   = (const float*)d_in[7];
    const float* Wo   = (const float*)d_in[8];
    const float* bo   = (const float*)d_in[9];
    float* out = (float*)d_out;

    // Workspace layout (bytes), total 160 MiB (== round-1 proven footprint):
    //  [0,   64M)  Q2d fp32
    //  [64M, 96M)  Xhi bf16            -> AObf bf16 (after V-GEMM)
    //  [96M,128M)  Xlo bf16            -> V2d fp32 [96M,112M) + Khi/Klo [112M,128M)
    //  [128M,144M) WqT hi+lo           -> WkT hi/lo + WvT + WoT (after Q-GEMM)
    //  [144M,160M) K2d fp32            -> Vt bf16 (after rope_k)
    char* ws = (char*)d_ws;
    float* Q2d   = (float*)(ws);
    short* Xhi   = (short*)(ws + 67108864);
    short* Xlo   = (short*)(ws + 100663296);
    short* WqThi = (short*)(ws + 134217728);
    short* WqTlo = (short*)(ws + 134217728 + 8388608);
    float* K2d   = (float*)(ws + 150994944);
    // overlays:
    float* V2d   = (float*)(ws + 100663296);              // over Xlo[0:16M)
    short* Khi   = (short*)(ws + 100663296 + 16777216);   // over Xlo[16M:24M)
    short* Klo   = (short*)(ws + 100663296 + 25165824);   // over Xlo[24M:32M)
    short* WkThi = (short*)(ws + 134217728);              // over WqT after Q-GEMM
    short* WkTlo = (short*)(ws + 134217728 + 2097152);
    short* WvThi = (short*)(ws + 134217728 + 4194304);
    short* WoThi = (short*)(ws + 134217728 + 8388608);
    short* Vt    = (short*)(ws + 150994944);              // over K2d after rope_k
    short* AObf  = (short*)(ws + 67108864);               // over Xhi after V-GEMM

    const int M = Bc * Tc;      // 8192
    dim3 blk(256);

    // 1) Wq^T split, x split
    transpose_split<<<dim3(Ec / 32, Ec / 32), blk, 0, stream>>>(Wq, WqThi, WqTlo, Ec, Ec);
    convert_split<<<(M * Ec / 4) / 256, blk, 0, stream>>>(x, Xhi, Xlo);
    // 2) Q projection (split, fp32-fidelity)
    gemm_mfma<true><<<dim3(M / 128, Ec / 128), blk, 0, stream>>>(
        Xhi, Xlo, WqThi, WqTlo, bq, Q2d, M, Ec, Ec);
    // 3) remaining weight transposes (into the now-dead WqT slab)
    transpose_split<<<dim3(Ec / 32, KVEc / 32), blk, 0, stream>>>(Wk, WkThi, WkTlo, Ec, KVEc);
    transpose_split<<<dim3(Ec / 32, KVEc / 32), blk, 0, stream>>>(Wv, WvThi, nullptr, Ec, KVEc);
    transpose_split<<<dim3(Ec / 32, Ec / 32), blk, 0, stream>>>(Wo, WoThi, nullptr, Ec, Ec);
    // 4) K projection (split), V projection (plain)
    gemm_mfma<true><<<dim3(M / 128, KVEc / 128), blk, 0, stream>>>(
        Xhi, Xlo, WkThi, WkTlo, bk, K2d, M, KVEc, Ec);
    gemm_mfma<false><<<dim3(M / 128, KVEc / 128), blk, 0, stream>>>(
        Xhi, nullptr, WvThi, nullptr, bv, V2d, M, KVEc, Ec);
    // 5) RoPE: K -> hi/lo bf16, V -> transposed bf16
    rope_k<<<(Bc * NKVc * Tc * 64) / 256, blk, 0, stream>>>(K2d, Khi, Klo);
    rope_v_t<<<dim3(Tc / 32, NKVc, Bc), blk, 0, stream>>>(V2d, Vt);
    // 6) attention -> bf16 AO
    attn_mfma<<<dim3(Tc / 64, NHc, Bc), blk, 0, stream>>>(Q2d, Khi, Klo, Vt, amask, AObf);
    // 7) output projection (plain)
    gemm_mfma<false><<<dim3(M / 128, Ec / 128), blk, 0, stream>>>(
        AObf, nullptr, WoThi, nullptr, bo, out, M, Ec, Ec);
}